// Round 12
// baseline (139.400 us; speedup 1.0000x reference)
//
#include <hip/hip_runtime.h>
#include <hip/hip_bf16.h>

// Problem constants: B=8, L=1024, D=1024, H=16, K=64
// Reference (bug reproduced): no softmax => linear attention:
//   out_b = Q_b @ U_b + b_out,  U_b[h*64+j, n] = sum_k S_bh[j,k] w_out[h*64+k, n],
//   S_bh = K_h^T V_h / 8.

typedef __attribute__((ext_vector_type(8))) short short8;
typedef __attribute__((ext_vector_type(4))) float f32x4;

static __device__ __forceinline__ short f2bf(float f) {
  __hip_bfloat16 h = __float2bfloat16(f);
  return __builtin_bit_cast(short, h);
}
static __device__ __forceinline__ float bf2f(short s) {
  unsigned int u = ((unsigned int)(unsigned short)s) << 16;
  return __builtin_bit_cast(float, u);
}

#define GLOAD16(src, dst)                                        \
  __builtin_amdgcn_global_load_lds(                              \
      (const __attribute__((address_space(1))) void*)(src),      \
      (__attribute__((address_space(3))) void*)(dst), 16, 0, 0)
#define BAR() __builtin_amdgcn_s_barrier()
#define SCHED() __builtin_amdgcn_sched_barrier(0)
#define WAIT_VM6() asm volatile("s_waitcnt vmcnt(6)" ::: "memory")
#define WAIT_VM5() asm volatile("s_waitcnt vmcnt(5)" ::: "memory")
#define WAIT_VM4() asm volatile("s_waitcnt vmcnt(4)" ::: "memory")
#define WAIT_VM0() asm volatile("s_waitcnt vmcnt(0)" ::: "memory")

// ---------------- fused prep: cast x -> bf16, transpose w_in / w_out -----
static __device__ __forceinline__ void transpose_body(
    const float* __restrict__ in, __hip_bfloat16* __restrict__ out,
    int R, int C, int c0, int r0, float tile[32][33]) {
  int tx = threadIdx.x & 31;
  int ty = threadIdx.x >> 5;  // 0..7
#pragma unroll
  for (int i = 0; i < 4; ++i)
    tile[ty + i * 8][tx] = in[(size_t)(r0 + ty + i * 8) * C + c0 + tx];
  __syncthreads();
#pragma unroll
  for (int i = 0; i < 4; ++i)
    out[(size_t)(c0 + ty + i * 8) * R + r0 + tx] =
        __float2bfloat16(tile[tx][ty + i * 8]);
}

__global__ __launch_bounds__(256) void prep_kernel(
    const float* __restrict__ x, __hip_bfloat16* __restrict__ x_bf,
    const float* __restrict__ w_in, __hip_bfloat16* __restrict__ w_inT,
    const float* __restrict__ w_out, __hip_bfloat16* __restrict__ w_outT) {
  __shared__ float tile[32][33];
  const int bx = blockIdx.x;
  if (bx < 4096) {
    size_t i = ((size_t)bx * 256 + threadIdx.x) * 8;
    float4 v0 = *(const float4*)(x + i);
    float4 v1 = *(const float4*)(x + i + 4);
    short8 o;
    o[0] = f2bf(v0.x); o[1] = f2bf(v0.y); o[2] = f2bf(v0.z); o[3] = f2bf(v0.w);
    o[4] = f2bf(v1.x); o[5] = f2bf(v1.y); o[6] = f2bf(v1.z); o[7] = f2bf(v1.w);
    *(short8*)((__hip_bfloat16*)x_bf + i) = o;
  } else if (bx < 4096 + 3072) {
    int b = bx - 4096;  // w_in: 1024 x 3072 -> 96 x 32 tiles
    transpose_body(w_in, w_inT, 1024, 3072, (b % 96) * 32, (b / 96) * 32, tile);
  } else {
    int b = bx - 7168;  // w_out: 1024 x 1024 -> 32 x 32 tiles
    transpose_body(w_out, w_outT, 1024, 1024, (b % 32) * 32, (b / 32) * 32, tile);
  }
}

// ---------------- GEMM1 v2: 512x192 block, wave 128x96 (LDS-economy) -----
// qkv = x_bf @ w_inT^T + b_in.  M=8192, N=3072, KD=1024, BK=32.
// 8 waves (4M x 2N), wave tile 128x96 = 8x6 frags 16x16x32 ->
// 0.29 KB LDS-read per MFMA (vs 0.5 for 64x64 waves): per-CU step
// LDS 437cyc vs MFMA 466cyc -- balanced, was 1.6x LDS-bound.
// Grid 16x16 = 256 blocks = EXACTLY 1/CU (132KB LDS, ~250 VGPR,
// 2 waves/SIMD): single scheduling round, zero tail.
// 3-buf pipeline: stage tile k+2 at top of step k; per-wave counted
// vmcnt (waves 0-3 carry 2 B-instr -> vmcnt(6), waves 4-7 -> vmcnt(5))
// + raw s_barrier.  T2 XOR swizzle kg' = kg ^ ((row>>1)&3) (conflict-free,
// R8-verified); 16-row frag stride => swizzle term constant across mi/ni
// => ds_read immediate offsets.
__global__ __launch_bounds__(512) void gemm1_kernel(
    const __hip_bfloat16* __restrict__ A, const __hip_bfloat16* __restrict__ Bt,
    const float* __restrict__ bias, __hip_bfloat16* __restrict__ C) {
  __shared__ __align__(16) __hip_bfloat16 As[3][512 * 32];  // 3 x 32 KB
  __shared__ __align__(16) __hip_bfloat16 Bs[3][192 * 32];  // 3 x 12 KB

  const int t = threadIdx.x;
  const int w = t >> 6, lane = t & 63;
  const int wm = w >> 1, wn = w & 1;
  const int lr = lane & 15, kg = lane >> 4;

  // XCD swizzle + 2x4 supertile (A 2MB + B 1.5MB < 4MB per-XCD L2)
  const int xcd = blockIdx.x & 7;
  const int c = blockIdx.x >> 3;            // 0..31
  const int bm = xcd * 2 + ((c >> 2) & 1);  // 0..15
  const int bn = (c >> 3) * 4 + (c & 3);    // 0..15
  const int m0 = bm * 512, n0 = bn * 192;

  // staging sources (granule = 8 bf16 = 16B; LDS slot (row,j) holds global
  // (row, j ^ ((row>>1)&3)) -- inverse-permuted source, linear LDS dest)
  const __hip_bfloat16* srcA[4];
#pragma unroll
  for (int i = 0; i < 4; ++i) {
    int g = w * 256 + i * 64 + lane;        // A: 2048 granules
    int row = g >> 2, j = (g & 3) ^ ((row >> 1) & 3);
    srcA[i] = A + (size_t)(m0 + row) * 1024 + j * 8;
  }
  const __hip_bfloat16* srcB0;
  const __hip_bfloat16* srcB1 = nullptr;
  {
    int g = w * 64 + lane;                  // B: 768 granules; instr0 covers 512
    int row = g >> 2, j = (g & 3) ^ ((row >> 1) & 3);
    srcB0 = Bt + (size_t)(n0 + row) * 1024 + j * 8;
  }
  if (w < 4) {                              // waves 0-3 stage granules 512..767
    int g = 512 + w * 64 + lane;
    int row = g >> 2, j = (g & 3) ^ ((row >> 1) & 3);
    srcB1 = Bt + (size_t)(n0 + row) * 1024 + j * 8;
  }

  auto stage = [&](int buf, int kt) {
    const int ko = kt * 32;
#pragma unroll
    for (int i = 0; i < 4; ++i)
      GLOAD16(srcA[i] + ko, &As[buf][(w * 256 + i * 64) * 8]);
    GLOAD16(srcB0 + ko, &Bs[buf][(w * 64) * 8]);
    if (w < 4) GLOAD16(srcB1 + ko, &Bs[buf][(512 + w * 64) * 8]);
  };

  // fragment base offsets; 16-row stride => +i*512 with same swizzle
  const int rA0 = wm * 128 + lr;
  const int offA0 = rA0 * 32 + (kg ^ ((rA0 >> 1) & 3)) * 8;
  const int rB0 = wn * 96 + lr;
  const int offB0 = rB0 * 32 + (kg ^ ((rB0 >> 1) & 3)) * 8;

  f32x4 acc[8][6] = {};
  constexpr int steps = 32;  // KD/BK

  // prologue: tiles 0,1 -> bufs 0,1; drain tile0 (per-wave count)
  stage(0, 0);
  stage(1, 1);
  SCHED();
  if (w < 4) WAIT_VM6(); else WAIT_VM5();
  BAR();
  SCHED();

  int cur = 0;
#pragma unroll 1
  for (int kt = 0; kt < steps; ++kt) {
    if (kt + 2 < steps) {
      int nb = cur + 2; if (nb >= 3) nb -= 3;
      stage(nb, kt + 2);
    }
    SCHED();
    const __hip_bfloat16* Ac = As[cur];
    const __hip_bfloat16* Bc = Bs[cur];
    short8 bfv[6];
#pragma unroll
    for (int ni = 0; ni < 6; ++ni)
      bfv[ni] = *(const short8*)&Bc[offB0 + ni * 512];
#pragma unroll
    for (int half = 0; half < 2; ++half) {
      short8 af[4];
#pragma unroll
      for (int mi = 0; mi < 4; ++mi)
        af[mi] = *(const short8*)&Ac[offA0 + (half * 4 + mi) * 512];
#pragma unroll
      for (int mi = 0; mi < 4; ++mi)
#pragma unroll
        for (int ni = 0; ni < 6; ++ni)
          acc[half * 4 + mi][ni] = __builtin_amdgcn_mfma_f32_16x16x32_bf16(
              af[mi], bfv[ni], acc[half * 4 + mi][ni], 0, 0, 0);
    }
    SCHED();
    if (kt < steps - 2) {
      if (w < 4) WAIT_VM6(); else WAIT_VM5();
    } else {
      WAIT_VM0();
    }
    BAR();
    SCHED();
    ++cur; if (cur == 3) cur = 0;
  }

  // C/D layout: col = lane&15, row = (lane>>4)*4 + reg
#pragma unroll
  for (int mi = 0; mi < 8; ++mi) {
    int row0 = m0 + wm * 128 + mi * 16 + kg * 4;
#pragma unroll
    for (int ni = 0; ni < 6; ++ni) {
      int col = n0 + wn * 96 + ni * 16 + lr;
      float bv = bias[col];
#pragma unroll
      for (int r = 0; r < 4; ++r)
        C[(size_t)(row0 + r) * 3072 + col] =
            __float2bfloat16(acc[mi][ni][r] + bv);
    }
  }
}

// ---------------- bf16 MFMA GEMM (R8-best, GEMM4' only) ------------------
// 128x128 tile, BK=32, 4 waves 64x64, 3-buf counted vmcnt, T2 swizzle.
template <int KD, int AS, int NBN, int NOUT, long BTB>
__global__ __launch_bounds__(256) void gemm_bt_kernel(
    const __hip_bfloat16* __restrict__ A, const __hip_bfloat16* __restrict__ Bt,
    const float* __restrict__ bias, float* __restrict__ C) {
  __shared__ __align__(16) __hip_bfloat16 As[3][128 * 32];
  __shared__ __align__(16) __hip_bfloat16 Bs[3][128 * 32];

  const int t = threadIdx.x;
  A += (size_t)blockIdx.y * 1024 * AS;
  Bt += (size_t)blockIdx.y * BTB;
  C += (size_t)blockIdx.y * 1024 * NOUT;

  const int cpx = gridDim.x >> 3;
  const int wg = (blockIdx.x & 7) * cpx + (blockIdx.x >> 3);
  const int bm = wg / NBN, bn = wg % NBN;
  const int m0 = bm * 128, n0 = bn * 128;

  const int w = t >> 6, lane = t & 63;
  const int wr = w >> 1, wc = w & 1;
  const int lr = lane & 15, kg = lane >> 4;

  const int g0 = w * 128 + lane;
  const int g1 = g0 + 64;
  const int r0g = g0 >> 2, j0g = (g0 & 3) ^ ((r0g >> 1) & 3);
  const int r1g = g1 >> 2, j1g = (g1 & 3) ^ ((r1g >> 1) & 3);
  const __hip_bfloat16* srcA0 = A + (size_t)(m0 + r0g) * AS + j0g * 8;
  const __hip_bfloat16* srcA1 = A + (size_t)(m0 + r1g) * AS + j1g * 8;
  const __hip_bfloat16* srcB0 = Bt + (size_t)(n0 + r0g) * KD + j0g * 8;
  const __hip_bfloat16* srcB1 = Bt + (size_t)(n0 + r1g) * KD + j1g * 8;
  const int lds0 = w * 128 * 8;
  const int lds1 = (w * 128 + 64) * 8;

  f32x4 acc[4][4] = {};
  constexpr int steps = KD / 32;

  auto stage = [&](int buf, int kt) {
    const int ko = kt * 32;
    GLOAD16(srcA0 + ko, &As[buf][lds0]);
    GLOAD16(srcA1 + ko, &As[buf][lds1]);
    GLOAD16(srcB0 + ko, &Bs[buf][lds0]);
    GLOAD16(srcB1 + ko, &Bs[buf][lds1]);
  };

  int offA[4], offB[4];
#pragma unroll
  for (int i = 0; i < 4; ++i) {
    int rowA = wr * 64 + i * 16 + lr;
    int rowB = wc * 64 + i * 16 + lr;
    offA[i] = rowA * 32 + (kg ^ ((rowA >> 1) & 3)) * 8;
    offB[i] = rowB * 32 + (kg ^ ((rowB >> 1) & 3)) * 8;
  }

  stage(0, 0);
  stage(1, 1);
  SCHED();
  WAIT_VM4();
  BAR();
  SCHED();

  int cur = 0;
#pragma unroll 1
  for (int kt = 0; kt < steps; ++kt) {
    if (kt + 2 < steps) {
      int nb = cur + 2; if (nb >= 3) nb -= 3;
      stage(nb, kt + 2);
    }
    SCHED();
    const __hip_bfloat16* Ac = As[cur];
    const __hip_bfloat16* Bc = Bs[cur];
    short8 af[4], bfv[4];
#pragma unroll
    for (int mi = 0; mi < 4; ++mi) af[mi] = *(const short8*)&Ac[offA[mi]];
#pragma unroll
    for (int ni = 0; ni < 4; ++ni) bfv[ni] = *(const short8*)&Bc[offB[ni]];
#pragma unroll
    for (int mi = 0; mi < 4; ++mi)
#pragma unroll
      for (int ni = 0; ni < 4; ++ni)
        acc[mi][ni] = __builtin_amdgcn_mfma_f32_16x16x32_bf16(
            af[mi], bfv[ni], acc[mi][ni], 0, 0, 0);
    SCHED();
    if (kt < steps - 2) WAIT_VM4(); else WAIT_VM0();
    BAR();
    SCHED();
    ++cur; if (cur == 3) cur = 0;
  }

#pragma unroll
  for (int mi = 0; mi < 4; ++mi) {
    int row0 = m0 + wr * 64 + mi * 16 + kg * 4;
#pragma unroll
    for (int ni = 0; ni < 4; ++ni) {
      int col = n0 + wc * 64 + ni * 16 + lr;
      float bv = bias[col];
#pragma unroll
      for (int r = 0; r < 4; ++r)
        C[(size_t)(row0 + r) * NOUT + col] = acc[mi][ni][r] + bv;
    }
  }
}

// ---------------- Spart[c][b,h] = K_h^T @ V_h over 256 L-rows ------------
__global__ __launch_bounds__(256) void ktv_kernel(
    const __hip_bfloat16* __restrict__ qkv, float* __restrict__ Spart) {
  __shared__ __align__(16) float Ks[64][68];
  __shared__ __align__(16) float Vs[64][68];
  const int bh = blockIdx.x;                 // 0..127
  const int ch = blockIdx.y;                 // 0..3
  const int b = bh >> 4, h = bh & 15;
  const __hip_bfloat16* base = qkv + (size_t)b * 1024 * 3072;
  const int hoff = h * 64;
  const int t = threadIdx.x;
  const int i0 = (t >> 4) * 4;
  const int j0 = (t & 15) * 4;
  const int srow = t >> 2;
  const int sg0 = t & 3;

  f32x4 acc[4] = {};

  for (int c = 0; c < 4; ++c) {
    int l0 = ch * 256 + c * 64;
#pragma unroll
    for (int rep = 0; rep < 2; ++rep) {
      int g = sg0 + rep * 4;
      const __hip_bfloat16* rowp = base + (size_t)(l0 + srow) * 3072;
      short8 kv = *(const short8*)(rowp + 1024 + hoff + g * 8);
      short8 vv = *(const short8*)(rowp + 2048 + hoff + g * 8);
      f32x4 k0, k1, v0, v1;
#pragma unroll
      for (int e = 0; e < 4; ++e) {
        k0[e] = bf2f(kv[e]); k1[e] = bf2f(kv[4 + e]);
        v0[e] = bf2f(vv[e]); v1[e] = bf2f(vv[4 + e]);
      }
      *(f32x4*)&Ks[srow][g * 8] = k0;
      *(f32x4*)&Ks[srow][g * 8 + 4] = k1;
      *(f32x4*)&Vs[srow][g * 8] = v0;
      *(f32x4*)&Vs[srow][g * 8 + 4] = v1;
    }
    __syncthreads();
#pragma unroll 8
    for (int l = 0; l < 64; ++l) {
      f32x4 kq = *(const f32x4*)&Ks[l][i0];
      f32x4 vq = *(const f32x4*)&Vs[l][j0];
#pragma unroll
      for (int ii = 0; ii < 4; ++ii) acc[ii] += kq[ii] * vq;
    }
    __syncthreads();
  }

  float* Sp = Spart + ((size_t)ch * 128 + bh) * 4096;
#pragma unroll
  for (int ii = 0; ii < 4; ++ii)
#pragma unroll
    for (int jj = 0; jj < 4; ++jj)
      Sp[(i0 + ii) * 64 + j0 + jj] = acc[ii][jj];
}

// ---------------- Ut_b[n][h*64+j] = sum_k (S_bh[j][k]/8) w_outT[n][h*64+k]
__global__ __launch_bounds__(256) void ut_kernel(
    const float* __restrict__ Spart, const __hip_bfloat16* __restrict__ w_outT,
    __hip_bfloat16* __restrict__ Ut) {
  __shared__ __align__(16) __hip_bfloat16 Sl[64][72];  // +8 pad
  const int bh = blockIdx.x;
  const int b = bh >> 4, h = bh & 15;
  const int t = threadIdx.x, w = t >> 6, lane = t & 63;
  const int lr = lane & 15, kg = lane >> 4;
  const int nbase = blockIdx.y * 512 + w * 128;

#pragma unroll
  for (int rep = 0; rep < 4; ++rep) {
    int e4 = t + rep * 256;
    int row = e4 >> 4, c4 = e4 & 15;
    f32x4 s = {};
#pragma unroll
    for (int c = 0; c < 4; ++c)
      s += *(const f32x4*)&Spart[((size_t)c * 128 + bh) * 4096 + row * 64 + c4 * 4];
    s *= 0.125f;
    __hip_bfloat16* p = &Sl[row][c4 * 4];
    p[0] = __float2bfloat16(s[0]); p[1] = __float2bfloat16(s[1]);
    p[2] = __float2bfloat16(s[2]); p[3] = __float2bfloat16(s[3]);
  }
  __syncthreads();

  const __hip_bfloat16* Ap = w_outT + (size_t)(nbase + lr) * 1024 + h * 64 + kg * 8;
  short8 bF[4][2];
#pragma unroll
  for (int ni = 0; ni < 4; ++ni)
#pragma unroll
    for (int kk = 0; kk < 2; ++kk)
      bF[ni][kk] = *(const short8*)&Sl[ni * 16 + lr][kk * 32 + kg * 8];

  f32x4 acc[8][4] = {};
#pragma unroll
  for (int mi = 0; mi < 8; ++mi) {
#pragma unroll
    for (int kk = 0; kk < 2; ++kk) {
      short8 aF = *(const short8*)(Ap + (size_t)mi * 16 * 1024 + kk * 32);
#pragma unroll
      for (int ni = 0; ni < 4; ++ni)
        acc[mi][ni] = __builtin_amdgcn_mfma_f32_16x16x32_bf16(
            aF, bF[ni][kk], acc[mi][ni], 0, 0, 0);
    }
  }

  __hip_bfloat16* Up = Ut + (size_t)b * 1024 * 1024;
#pragma unroll
  for (int mi = 0; mi < 8; ++mi) {
    int row0 = nbase + mi * 16 + kg * 4;
#pragma unroll
    for (int ni = 0; ni < 4; ++ni) {
      int col = h * 64 + ni * 16 + lr;
#pragma unroll
      for (int r = 0; r < 4; ++r)
        Up[(size_t)(row0 + r) * 1024 + col] = __float2bfloat16(acc[mi][ni][r]);
    }
  }
}

extern "C" void kernel_launch(void* const* d_in, const int* in_sizes, int n_in,
                              void* d_out, int out_size, void* d_ws, size_t ws_size,
                              hipStream_t stream) {
  const float* x = (const float*)d_in[0];
  const float* w_in = (const float*)d_in[1];
  const float* b_in = (const float*)d_in[2];
  const float* w_out = (const float*)d_in[3];
  const float* b_out = (const float*)d_in[4];
  float* out = (float*)d_out;

  char* ws = (char*)d_ws;
  __hip_bfloat16* x_bf = (__hip_bfloat16*)ws;   ws += (size_t)8192 * 1024 * 2;
  __hip_bfloat16* w_inT = (__hip_bfloat16*)ws;  ws += (size_t)3072 * 1024 * 2;
  __hip_bfloat16* w_outT = (__hip_bfloat16*)ws; ws += (size_t)1024 * 1024 * 2;
  __hip_bfloat16* qkv = (__hip_bfloat16*)ws;    ws += (size_t)8192 * 3072 * 2;
  float* Spart = (float*)ws;                    ws += (size_t)4 * 128 * 64 * 64 * 4;
  __hip_bfloat16* Ut = (__hip_bfloat16*)ws;     ws += (size_t)8 * 1024 * 1024 * 2;

  // fused prep: cast x (4096 blocks) + transpose w_in (3072) + w_out (1024)
  prep_kernel<<<8192, 256, 0, stream>>>(x, x_bf, w_in, w_inT, w_out, w_outT);

  // GEMM1: qkv = x @ w_in + b_in  (8192 x 3072, KD=1024) -> bf16
  // 256 blocks x 512 thr = exactly 1 block/CU, single round.
  gemm1_kernel<<<256, 512, 0, stream>>>(x_bf, w_inT, b_in, qkv);

  // S partials = Kt V per (b,h) over 256-row chunks (512 blocks = 2/CU)
  ktv_kernel<<<dim3(128, 4), 256, 0, stream>>>(qkv, Spart);

  // Ut_b = (S_bh/8 @ Wout_h)^T stacked  -> bf16 (8 x 1024 x 1024)
  ut_kernel<<<dim3(128, 2), 256, 0, stream>>>(Spart, w_outT, Ut);

  // GEMM4': out_b = Q_b @ U_b + b_out  (8 batched 1024x1024, A stride 3072,
  //         Bt batch stride 1024*1024)
  gemm_bt_kernel<1024, 3072, 8, 1024, 1024 * 1024>
      <<<dim3(64, 8), 256, 0, stream>>>(qkv, Ut, b_out, out);
}

// Round 13
// 136.893 us; speedup vs baseline: 1.0183x; 1.0183x over previous
//
#include <hip/hip_runtime.h>
#include <hip/hip_bf16.h>

// Problem constants: B=8, L=1024, D=1024, H=16, K=64
// Reference (bug reproduced): no softmax => linear attention:
//   out_b = Q_b @ U_b + b_out,  U_b[h*64+j, n] = sum_k S_bh[j,k] w_out[h*64+k, n],
//   S_bh = K_h^T V_h / 8.
//
// R12 post-mortem ledger (why this exact config):
//  - GEMM1 structure: 128x128/BK32/4-wave/3-buf counted-vmcnt/T2-swizzle.
//    Verified: conflicts=0 (R8), FETCH 41MB (supertile, R8), 72.5us stable.
//    Rejected by measurement: 8-phase 256^2 (R3: 90us, K too short),
//    32x32x16+BK64 (R6: 89us, staging sectors), reg-staged A (R9: 87us,
//    T14 prereq cost), 512x192 1-block/CU (R12: 80us, barrier-lockstep).

typedef __attribute__((ext_vector_type(8))) short short8;
typedef __attribute__((ext_vector_type(4))) float f32x4;

static __device__ __forceinline__ short f2bf(float f) {
  __hip_bfloat16 h = __float2bfloat16(f);
  return __builtin_bit_cast(short, h);
}
static __device__ __forceinline__ float bf2f(short s) {
  unsigned int u = ((unsigned int)(unsigned short)s) << 16;
  return __builtin_bit_cast(float, u);
}

#define GLOAD16(src, dst)                                        \
  __builtin_amdgcn_global_load_lds(                              \
      (const __attribute__((address_space(1))) void*)(src),      \
      (__attribute__((address_space(3))) void*)(dst), 16, 0, 0)
#define BAR() __builtin_amdgcn_s_barrier()
#define SCHED() __builtin_amdgcn_sched_barrier(0)
#define WAIT_VM4() asm volatile("s_waitcnt vmcnt(4)" ::: "memory")
#define WAIT_VM0() asm volatile("s_waitcnt vmcnt(0)" ::: "memory")

// ---------------- fused prep: cast x -> bf16, transpose w_in / w_out -----
static __device__ __forceinline__ void transpose_body(
    const float* __restrict__ in, __hip_bfloat16* __restrict__ out,
    int R, int C, int c0, int r0, float tile[32][33]) {
  int tx = threadIdx.x & 31;
  int ty = threadIdx.x >> 5;  // 0..7
#pragma unroll
  for (int i = 0; i < 4; ++i)
    tile[ty + i * 8][tx] = in[(size_t)(r0 + ty + i * 8) * C + c0 + tx];
  __syncthreads();
#pragma unroll
  for (int i = 0; i < 4; ++i)
    out[(size_t)(c0 + ty + i * 8) * R + r0 + tx] =
        __float2bfloat16(tile[tx][ty + i * 8]);
}

__global__ __launch_bounds__(256) void prep_kernel(
    const float* __restrict__ x, __hip_bfloat16* __restrict__ x_bf,
    const float* __restrict__ w_in, __hip_bfloat16* __restrict__ w_inT,
    const float* __restrict__ w_out, __hip_bfloat16* __restrict__ w_outT) {
  __shared__ float tile[32][33];
  const int bx = blockIdx.x;
  if (bx < 4096) {
    size_t i = ((size_t)bx * 256 + threadIdx.x) * 8;
    float4 v0 = *(const float4*)(x + i);
    float4 v1 = *(const float4*)(x + i + 4);
    short8 o;
    o[0] = f2bf(v0.x); o[1] = f2bf(v0.y); o[2] = f2bf(v0.z); o[3] = f2bf(v0.w);
    o[4] = f2bf(v1.x); o[5] = f2bf(v1.y); o[6] = f2bf(v1.z); o[7] = f2bf(v1.w);
    *(short8*)((__hip_bfloat16*)x_bf + i) = o;
  } else if (bx < 4096 + 3072) {
    int b = bx - 4096;  // w_in: 1024 x 3072 -> 96 x 32 tiles
    transpose_body(w_in, w_inT, 1024, 3072, (b % 96) * 32, (b / 96) * 32, tile);
  } else {
    int b = bx - 7168;  // w_out: 1024 x 1024 -> 32 x 32 tiles
    transpose_body(w_out, w_outT, 1024, 1024, (b % 32) * 32, (b / 32) * 32, tile);
  }
}

// ---------------- bf16 MFMA GEMM (R8-best): 3-buf counted-vmcnt + T2 -----
// 128x128 tile, BK=32, 4 waves 64x64 = 4x4 frags 16x16x32.
// Stage tile k+2 at top of step k; vmcnt(4) + raw s_barrier per step.
// LDS [128][32] bf16, kg' = kg ^ ((row>>1)&3) XOR swizzle (conflicts=0,
// R8-verified); gload_lds dest linear, source inverse-permuted (m173).
// GEMM1 (NBN==24): 4x4 supertile ordering per XCD chunk (FETCH 41MB, R8).
static __device__ __forceinline__ void store_out(__hip_bfloat16* p, float v) {
  *p = __float2bfloat16(v);
}
static __device__ __forceinline__ void store_out(float* p, float v) { *p = v; }

template <typename OutT, int KD, int AS, int NBN, int NOUT, long BTB>
__global__ __launch_bounds__(256) void gemm_bt_kernel(
    const __hip_bfloat16* __restrict__ A, const __hip_bfloat16* __restrict__ Bt,
    const float* __restrict__ bias, OutT* __restrict__ C) {
  __shared__ __align__(16) __hip_bfloat16 As[3][128 * 32];
  __shared__ __align__(16) __hip_bfloat16 Bs[3][128 * 32];

  const int t = threadIdx.x;
  A += (size_t)blockIdx.y * 1024 * AS;
  Bt += (size_t)blockIdx.y * BTB;
  C += (size_t)blockIdx.y * 1024 * NOUT;

  const int xcd = blockIdx.x & 7;
  const int c = blockIdx.x >> 3;
  int bm, bn;
  if constexpr (NBN == 24) {
    const int st = c >> 4;
    const int im = (c >> 2) & 3, in_ = c & 3;
    bm = xcd * 8 + (st & 1) * 4 + im;
    bn = (st >> 1) * 4 + in_;
  } else {
    const int cpx = gridDim.x >> 3;
    const int wg = xcd * cpx + c;
    bm = wg / NBN; bn = wg % NBN;
  }
  const int m0 = bm * 128, n0 = bn * 128;

  const int w = t >> 6, lane = t & 63;
  const int wr = w >> 1, wc = w & 1;
  const int lr = lane & 15, kg = lane >> 4;

  const int g0 = w * 128 + lane;
  const int g1 = g0 + 64;
  const int r0g = g0 >> 2, j0g = (g0 & 3) ^ ((r0g >> 1) & 3);
  const int r1g = g1 >> 2, j1g = (g1 & 3) ^ ((r1g >> 1) & 3);
  const __hip_bfloat16* srcA0 = A + (size_t)(m0 + r0g) * AS + j0g * 8;
  const __hip_bfloat16* srcA1 = A + (size_t)(m0 + r1g) * AS + j1g * 8;
  const __hip_bfloat16* srcB0 = Bt + (size_t)(n0 + r0g) * KD + j0g * 8;
  const __hip_bfloat16* srcB1 = Bt + (size_t)(n0 + r1g) * KD + j1g * 8;
  const int lds0 = w * 128 * 8;
  const int lds1 = (w * 128 + 64) * 8;

  f32x4 acc[4][4] = {};
  constexpr int steps = KD / 32;

  auto stage = [&](int buf, int kt) {
    const int ko = kt * 32;
    GLOAD16(srcA0 + ko, &As[buf][lds0]);
    GLOAD16(srcA1 + ko, &As[buf][lds1]);
    GLOAD16(srcB0 + ko, &Bs[buf][lds0]);
    GLOAD16(srcB1 + ko, &Bs[buf][lds1]);
  };

  int offA[4], offB[4];
#pragma unroll
  for (int i = 0; i < 4; ++i) {
    int rowA = wr * 64 + i * 16 + lr;
    int rowB = wc * 64 + i * 16 + lr;
    offA[i] = rowA * 32 + (kg ^ ((rowA >> 1) & 3)) * 8;
    offB[i] = rowB * 32 + (kg ^ ((rowB >> 1) & 3)) * 8;
  }

  stage(0, 0);
  stage(1, 1);
  SCHED();
  WAIT_VM4();
  BAR();
  SCHED();

  int cur = 0;
#pragma unroll 1
  for (int kt = 0; kt < steps; ++kt) {
    if (kt + 2 < steps) {
      int nb = cur + 2; if (nb >= 3) nb -= 3;
      stage(nb, kt + 2);
    }
    SCHED();
    const __hip_bfloat16* Ac = As[cur];
    const __hip_bfloat16* Bc = Bs[cur];
    short8 af[4], bfv[4];
#pragma unroll
    for (int mi = 0; mi < 4; ++mi) af[mi] = *(const short8*)&Ac[offA[mi]];
#pragma unroll
    for (int ni = 0; ni < 4; ++ni) bfv[ni] = *(const short8*)&Bc[offB[ni]];
#pragma unroll
    for (int mi = 0; mi < 4; ++mi)
#pragma unroll
      for (int ni = 0; ni < 4; ++ni)
        acc[mi][ni] = __builtin_amdgcn_mfma_f32_16x16x32_bf16(
            af[mi], bfv[ni], acc[mi][ni], 0, 0, 0);
    SCHED();
    if (kt < steps - 2) WAIT_VM4(); else WAIT_VM0();
    BAR();
    SCHED();
    ++cur; if (cur == 3) cur = 0;
  }

#pragma unroll
  for (int mi = 0; mi < 4; ++mi) {
    int row0 = m0 + wr * 64 + mi * 16 + kg * 4;
#pragma unroll
    for (int ni = 0; ni < 4; ++ni) {
      int col = n0 + wc * 64 + ni * 16 + lr;
      float bv = bias[col];
#pragma unroll
      for (int r = 0; r < 4; ++r)
        store_out(&C[(size_t)(row0 + r) * NOUT + col], acc[mi][ni][r] + bv);
    }
  }
}

// ---------------- Spart[c][b,h] = K_h^T @ V_h over 256 L-rows ------------
__global__ __launch_bounds__(256) void ktv_kernel(
    const __hip_bfloat16* __restrict__ qkv, float* __restrict__ Spart) {
  __shared__ __align__(16) float Ks[64][68];
  __shared__ __align__(16) float Vs[64][68];
  const int bh = blockIdx.x;
  const int ch = blockIdx.y;
  const int b = bh >> 4, h = bh & 15;
  const __hip_bfloat16* base = qkv + (size_t)b * 1024 * 3072;
  const int hoff = h * 64;
  const int t = threadIdx.x;
  const int i0 = (t >> 4) * 4;
  const int j0 = (t & 15) * 4;
  const int srow = t >> 2;
  const int sg0 = t & 3;

  f32x4 acc[4] = {};

  for (int c = 0; c < 4; ++c) {
    int l0 = ch * 256 + c * 64;
#pragma unroll
    for (int rep = 0; rep < 2; ++rep) {
      int g = sg0 + rep * 4;
      const __hip_bfloat16* rowp = base + (size_t)(l0 + srow) * 3072;
      short8 kv = *(const short8*)(rowp + 1024 + hoff + g * 8);
      short8 vv = *(const short8*)(rowp + 2048 + hoff + g * 8);
      f32x4 k0, k1, v0, v1;
#pragma unroll
      for (int e = 0; e < 4; ++e) {
        k0[e] = bf2f(kv[e]); k1[e] = bf2f(kv[4 + e]);
        v0[e] = bf2f(vv[e]); v1[e] = bf2f(vv[4 + e]);
      }
      *(f32x4*)&Ks[srow][g * 8] = k0;
      *(f32x4*)&Ks[srow][g * 8 + 4] = k1;
      *(f32x4*)&Vs[srow][g * 8] = v0;
      *(f32x4*)&Vs[srow][g * 8 + 4] = v1;
    }
    __syncthreads();
#pragma unroll 8
    for (int l = 0; l < 64; ++l) {
      f32x4 kq = *(const f32x4*)&Ks[l][i0];
      f32x4 vq = *(const f32x4*)&Vs[l][j0];
#pragma unroll
      for (int ii = 0; ii < 4; ++ii) acc[ii] += kq[ii] * vq;
    }
    __syncthreads();
  }

  float* Sp = Spart + ((size_t)ch * 128 + bh) * 4096;
#pragma unroll
  for (int ii = 0; ii < 4; ++ii)
#pragma unroll
    for (int jj = 0; jj < 4; ++jj)
      Sp[(i0 + ii) * 64 + j0 + jj] = acc[ii][jj];
}

// ---------------- Ut_b[n][h*64+j] = sum_k (S_bh[j][k]/8) w_outT[n][h*64+k]
__global__ __launch_bounds__(256) void ut_kernel(
    const float* __restrict__ Spart, const __hip_bfloat16* __restrict__ w_outT,
    __hip_bfloat16* __restrict__ Ut) {
  __shared__ __align__(16) __hip_bfloat16 Sl[64][72];
  const int bh = blockIdx.x;
  const int b = bh >> 4, h = bh & 15;
  const int t = threadIdx.x, w = t >> 6, lane = t & 63;
  const int lr = lane & 15, kg = lane >> 4;
  const int nbase = blockIdx.y * 512 + w * 128;

#pragma unroll
  for (int rep = 0; rep < 4; ++rep) {
    int e4 = t + rep * 256;
    int row = e4 >> 4, c4 = e4 & 15;
    f32x4 s = {};
#pragma unroll
    for (int c = 0; c < 4; ++c)
      s += *(const f32x4*)&Spart[((size_t)c * 128 + bh) * 4096 + row * 64 + c4 * 4];
    s *= 0.125f;
    __hip_bfloat16* p = &Sl[row][c4 * 4];
    p[0] = __float2bfloat16(s[0]); p[1] = __float2bfloat16(s[1]);
    p[2] = __float2bfloat16(s[2]); p[3] = __float2bfloat16(s[3]);
  }
  __syncthreads();

  const __hip_bfloat16* Ap = w_outT + (size_t)(nbase + lr) * 1024 + h * 64 + kg * 8;
  short8 bF[4][2];
#pragma unroll
  for (int ni = 0; ni < 4; ++ni)
#pragma unroll
    for (int kk = 0; kk < 2; ++kk)
      bF[ni][kk] = *(const short8*)&Sl[ni * 16 + lr][kk * 32 + kg * 8];

  f32x4 acc[8][4] = {};
#pragma unroll
  for (int mi = 0; mi < 8; ++mi) {
#pragma unroll
    for (int kk = 0; kk < 2; ++kk) {
      short8 aF = *(const short8*)(Ap + (size_t)mi * 16 * 1024 + kk * 32);
#pragma unroll
      for (int ni = 0; ni < 4; ++ni)
        acc[mi][ni] = __builtin_amdgcn_mfma_f32_16x16x32_bf16(
            aF, bF[ni][kk], acc[mi][ni], 0, 0, 0);
    }
  }

  __hip_bfloat16* Up = Ut + (size_t)b * 1024 * 1024;
#pragma unroll
  for (int mi = 0; mi < 8; ++mi) {
    int row0 = nbase + mi * 16 + kg * 4;
#pragma unroll
    for (int ni = 0; ni < 4; ++ni) {
      int col = h * 64 + ni * 16 + lr;
#pragma unroll
      for (int r = 0; r < 4; ++r)
        Up[(size_t)(row0 + r) * 1024 + col] = __float2bfloat16(acc[mi][ni][r]);
    }
  }
}

extern "C" void kernel_launch(void* const* d_in, const int* in_sizes, int n_in,
                              void* d_out, int out_size, void* d_ws, size_t ws_size,
                              hipStream_t stream) {
  const float* x = (const float*)d_in[0];
  const float* w_in = (const float*)d_in[1];
  const float* b_in = (const float*)d_in[2];
  const float* w_out = (const float*)d_in[3];
  const float* b_out = (const float*)d_in[4];
  float* out = (float*)d_out;

  char* ws = (char*)d_ws;
  __hip_bfloat16* x_bf = (__hip_bfloat16*)ws;   ws += (size_t)8192 * 1024 * 2;
  __hip_bfloat16* w_inT = (__hip_bfloat16*)ws;  ws += (size_t)3072 * 1024 * 2;
  __hip_bfloat16* w_outT = (__hip_bfloat16*)ws; ws += (size_t)1024 * 1024 * 2;
  __hip_bfloat16* qkv = (__hip_bfloat16*)ws;    ws += (size_t)8192 * 3072 * 2;
  float* Spart = (float*)ws;                    ws += (size_t)4 * 128 * 64 * 64 * 4;
  __hip_bfloat16* Ut = (__hip_bfloat16*)ws;     ws += (size_t)8 * 1024 * 1024 * 2;

  // fused prep: cast x (4096 blocks) + transpose w_in (3072) + w_out (1024)
  prep_kernel<<<8192, 256, 0, stream>>>(x, x_bf, w_in, w_inT, w_out, w_outT);

  // GEMM1: qkv = x @ w_in + b_in  (8192 x 3072, KD=1024) -> bf16
  gemm_bt_kernel<__hip_bfloat16, 1024, 1024, 24, 3072, 0>
      <<<dim3(1536, 1), 256, 0, stream>>>(x_bf, w_inT, b_in, qkv);

  // S partials = Kt V per (b,h) over 256-row chunks (512 blocks = 2/CU)
  ktv_kernel<<<dim3(128, 4), 256, 0, stream>>>(qkv, Spart);

  // Ut_b = (S_bh/8 @ Wout_h)^T stacked  -> bf16 (8 x 1024 x 1024)
  ut_kernel<<<dim3(128, 2), 256, 0, stream>>>(Spart, w_outT, Ut);

  // GEMM4': out_b = Q_b @ U_b + b_out  (8 batched 1024x1024, A stride 3072,
  //         Bt batch stride 1024*1024) -> fp32
  gemm_bt_kernel<float, 1024, 3072, 8, 1024, 1024 * 1024>
      <<<dim3(64, 8), 256, 0, stream>>>(qkv, Ut, b_out, out);
}